// Round 2
// baseline (112.254 us; speedup 1.0000x reference)
//
#include <hip/hip_runtime.h>
#include <math.h>

#define N_FILT   80
#define FILT_DIM 251
#define KPAD     256
#define SIG_LEN  32000
#define OUT_LEN  31750
#define BATCH    32
#define TPB      256

#define STRIP    1024      // t-range per block
#define WAVE_T   256       // t-range per wave (4 waves)
#define NT       16        // 16x16 tiles per wave
#define NREP     8         // shifted replicas -> every window is 16B aligned
#define LROW     644       // dwords per replica: %4==0 (16B align), /4 odd (bank spread), >=640

#define TWO_PI_F 6.28318530717958647692f

typedef __attribute__((ext_vector_type(8))) short    short8;   // raw 16B frag
typedef __attribute__((ext_vector_type(8))) _Float16 half8;    // fp16 A/B frag
typedef __attribute__((ext_vector_type(4))) float    float4v;  // C/D frag

// ---------------------------------------------------------------------------
// Kernel 1: build 80 sinc band-pass filters directly in fp16.
// Layout: fh[80][256] (k padded with zeros) in d_ws.
// ---------------------------------------------------------------------------
__global__ __launch_bounds__(TPB) void build_filters_kernel(
    const float* __restrict__ b1, const float* __restrict__ band,
    unsigned short* __restrict__ fh)
{
    const int f = blockIdx.x;
    const int i = threadIdx.x;

    const float MINF = 50.0f / 16000.0f;
    const float fb = fabsf(b1[f]) + MINF;
    const float fe = fb + fabsf(band[f]) + MINF;

    float v = 0.0f;
    if (i < FILT_DIM) {
        int m = i - 125; m = (m < 0) ? -m : m;
        if (m == 0) v = 2.0f * fe - 2.0f * fb;
        else {
            float a1 = TWO_PI_F * fb * (float)m;
            float a2 = TWO_PI_F * fe * (float)m;
            v = 2.0f * fe * (sinf(a2) / a2) - 2.0f * fb * (sinf(a1) / a1);
        }
    }

    __shared__ float red[TPB];
    red[i] = (i < FILT_DIM) ? v : -INFINITY;
    __syncthreads();
    #pragma unroll
    for (int s = TPB / 2; s > 0; s >>= 1) {
        if (i < s) red[i] = fmaxf(red[i], red[i + s]);
        __syncthreads();
    }
    const float mx = red[0];

    const float w   = 0.54f - 0.46f * cosf(TWO_PI_F * (float)i / 250.0f);
    const float val = (i < FILT_DIM) ? (v / mx) * w : 0.0f;
    const _Float16 h = (_Float16)val;                 // RNE v_cvt_f16_f32
    fh[f * KPAD + i] = __builtin_bit_cast(unsigned short, h);  // pad rows = 0
}

// ---------------------------------------------------------------------------
// Kernel 2: conv as MFMA GEMM, single fp16 product.  C[f,t] = sum_k F[f,k]*x[t+k]
//   A (16 f x 32 k)  = fp16 filters, register-resident fragments
//   B (32 k x 16 t)  = Toeplitz x from LDS; 8 shift-replicated fp16 copies
//                      so every lane's 8-element window is one aligned
//                      ds_read_b128.
//   Toeplitz reuse: fragment for (tt,kb) depends only on u = tt + 2*kb
//                   -> rolling 16-slot register window, 30 LDS reads/wave
//                   instead of 128 (4.27x LDS traffic cut).
// Block: 4 waves x 256 t = 1024 t, one f-block (16 filters), one batch n.
// ---------------------------------------------------------------------------
__global__ __launch_bounds__(TPB) void sinc_mfma_kernel(
    const float* __restrict__ x,
    const unsigned short* __restrict__ fh,
    float* __restrict__ out)
{
    __shared__ __align__(16) unsigned xf[NREP * LROW];  // fp16 pairs in dwords

    const int tid   = threadIdx.x;
    const int strip = blockIdx.x;
    const int fb    = blockIdx.y;
    const int n     = blockIdx.z;
    const int e0    = strip * STRIP;
    const float* xp = x + (size_t)n * SIG_LEN;

    // ---- stage x: fp16, 8 shifted replicas (replica r, dword d = elems 2d+r,2d+r+1)
    for (int d = tid; d < LROW; d += TPB) {
        const int g = e0 + 2 * d;
        float v0, v1, v2;
        if (g + 2 < SIG_LEN) {
            float2 p = *(const float2*)(xp + g);
            v0 = p.x; v1 = p.y; v2 = xp[g + 2];
        } else {
            v0 = (g     < SIG_LEN) ? xp[g]     : 0.0f;
            v1 = (g + 1 < SIG_LEN) ? xp[g + 1] : 0.0f;
            v2 = (g + 2 < SIG_LEN) ? xp[g + 2] : 0.0f;
        }
        const _Float16 h0 = (_Float16)v0, h1 = (_Float16)v1, h2 = (_Float16)v2;
        union { _Float16 h[2]; unsigned u; } pe, po;
        pe.h[0] = h0; pe.h[1] = h1;          // elems 2d, 2d+1
        po.h[0] = h1; po.h[1] = h2;          // elems 2d+1, 2d+2
        xf[0 * LROW + d] = pe.u;                                  // r=0
        xf[1 * LROW + d] = po.u;                                  // r=1
        if (d >= 1) { xf[2 * LROW + d - 1] = pe.u;                // r=2
                      xf[3 * LROW + d - 1] = po.u; }              // r=3
        if (d >= 2) { xf[4 * LROW + d - 2] = pe.u;                // r=4
                      xf[5 * LROW + d - 2] = po.u; }              // r=5
        if (d >= 3) { xf[6 * LROW + d - 3] = pe.u;                // r=6
                      xf[7 * LROW + d - 3] = po.u; }              // r=7
    }

    // ---- A fragments: 16 filters x 256 k, fp16, from global (L2-resident) ---
    const int lane = tid & 63;
    const int w    = tid >> 6;
    const int m    = lane & 15;       // A-row (f) / B-col (t) / C-col (t)
    const int q    = lane >> 4;       // quad: k = q*8+j ; C-row = q*4+reg
    short8 Ah[8];
    {
        const unsigned short* ph = fh + (fb * 16 + m) * KPAD + q * 8;
        #pragma unroll
        for (int kb = 0; kb < 8; ++kb)
            Ah[kb] = *(const short8*)(ph + kb * 32);
    }
    __syncthreads();

    // ---- main loop ---------------------------------------------------------
    // element start s = 256w + 16tt + m + 8q + 32kb ; replica r = m&7
    // dword idx = LROW*r + (s-r)/2 = LROW*r + 128w + 8*(tt+2kb) + 4*(m>>3) + 4q
    // (LROW/4 = 161 odd  ->  r*LROW spreads all 8 quad-bank groups: per b128
    //  instruction exactly 8 lanes per 128B bank group = conflict-free)
    const int r = m & 7;
    const unsigned base = (unsigned)(r * LROW + 4 * (m >> 3) + 4 * q + 128 * w);

    // Rolling register window of B fragments, keyed by u = tt + 2*kb (u&15).
    // All indices compile-time after full unroll -> stays in VGPRs.
    uint4 Bf[16];
    #pragma unroll
    for (int u = 0; u < 16; ++u)
        Bf[u] = *(const uint4*)(&xf[base + 8u * u]);   // note: 8*u dwords

    #pragma unroll
    for (int tt = 0; tt < NT; ++tt) {
        if (tt >= 2)   // fragment u = tt+14 replaces dead u = tt-2
            Bf[(tt + 14) & 15] = *(const uint4*)(&xf[base + 8u * (tt + 14)]);

        float4v acc = {0.f, 0.f, 0.f, 0.f};
        #pragma unroll
        for (int kb = 0; kb < 8; ++kb) {
            acc = __builtin_amdgcn_mfma_f32_16x16x32_f16(
                      __builtin_bit_cast(half8, Ah[kb]),
                      __builtin_bit_cast(half8, Bf[(tt + 2 * kb) & 15]),
                      acc, 0, 0, 0);
        }

        const int t = e0 + w * WAVE_T + tt * 16 + m;   // C col
        if (t < OUT_LEN) {
            const size_t rowbase =
                ((size_t)n * N_FILT + fb * 16 + q * 4) * OUT_LEN + t;
            #pragma unroll
            for (int rg = 0; rg < 4; ++rg)
                out[rowbase + (size_t)rg * OUT_LEN] = acc[rg];
        }
    }
}

// ---------------------------------------------------------------------------
extern "C" void kernel_launch(void* const* d_in, const int* in_sizes, int n_in,
                              void* d_out, int out_size, void* d_ws, size_t ws_size,
                              hipStream_t stream)
{
    const float* x    = (const float*)d_in[0];
    const float* b1   = (const float*)d_in[1];
    const float* band = (const float*)d_in[2];
    float* outp = (float*)d_out;

    unsigned short* fh = (unsigned short*)d_ws;          // 80*256*2 B = 40 KB

    build_filters_kernel<<<dim3(N_FILT), dim3(TPB), 0, stream>>>(b1, band, fh);

    dim3 grid((OUT_LEN + STRIP - 1) / STRIP, N_FILT / 16, BATCH);   // 32 x 5 x 32
    sinc_mfma_kernel<<<grid, dim3(TPB), 0, stream>>>(x, fh, outp);
}

// Round 3
// 109.804 us; speedup vs baseline: 1.0223x; 1.0223x over previous
//
#include <hip/hip_runtime.h>
#include <math.h>

#define N_FILT   80
#define FILT_DIM 251
#define KPAD     256
#define SIG_LEN  32000
#define OUT_LEN  31750
#define BATCH    32
#define TPB      256

#define STRIP    1024      // t-range per block
#define WAVE_T   256       // t-range per wave (4 waves)
#define NREP     8         // shifted replicas -> every window is 16B aligned
#define LROW     644       // dwords per replica: %4==0 (16B align), /4 odd (bank spread), >=640

#define TWO_PI_F 6.28318530717958647692f

typedef __attribute__((ext_vector_type(8))) short    short8;   // raw 16B frag
typedef __attribute__((ext_vector_type(8))) _Float16 half8;    // fp16 A/B frag
typedef __attribute__((ext_vector_type(4))) float    float4v;  // C/D frag

// ---------------------------------------------------------------------------
// Kernel 1: build 80 sinc band-pass filters directly in fp16.
// Layout: fh[80][256] (k padded with zeros) in d_ws.
// ---------------------------------------------------------------------------
__global__ __launch_bounds__(TPB) void build_filters_kernel(
    const float* __restrict__ b1, const float* __restrict__ band,
    unsigned short* __restrict__ fh)
{
    const int f = blockIdx.x;
    const int i = threadIdx.x;

    const float MINF = 50.0f / 16000.0f;
    const float fb = fabsf(b1[f]) + MINF;
    const float fe = fb + fabsf(band[f]) + MINF;

    float v = 0.0f;
    if (i < FILT_DIM) {
        int m = i - 125; m = (m < 0) ? -m : m;
        if (m == 0) v = 2.0f * fe - 2.0f * fb;
        else {
            float a1 = TWO_PI_F * fb * (float)m;
            float a2 = TWO_PI_F * fe * (float)m;
            v = 2.0f * fe * (sinf(a2) / a2) - 2.0f * fb * (sinf(a1) / a1);
        }
    }

    __shared__ float red[TPB];
    red[i] = (i < FILT_DIM) ? v : -INFINITY;
    __syncthreads();
    #pragma unroll
    for (int s = TPB / 2; s > 0; s >>= 1) {
        if (i < s) red[i] = fmaxf(red[i], red[i + s]);
        __syncthreads();
    }
    const float mx = red[0];

    const float w   = 0.54f - 0.46f * cosf(TWO_PI_F * (float)i / 250.0f);
    const float val = (i < FILT_DIM) ? (v / mx) * w : 0.0f;
    const _Float16 h = (_Float16)val;                 // RNE v_cvt_f16_f32
    fh[f * KPAD + i] = __builtin_bit_cast(unsigned short, h);  // pad rows = 0
}

// ---------------------------------------------------------------------------
// Kernel 2: conv as MFMA GEMM, single fp16 product.  C[f,t] = sum_k F[f,k]*x[t+k]
//   A (16 f x 32 k)  = fp16 filters, register-resident fragments
//   B (32 k x 16 t)  = Toeplitz x from LDS (8 shift-replicated fp16 copies,
//                      each window one aligned ds_read_b128).
//   Latency fix (R3): process TWO t-tiles (tt2, tt2+8) per iteration with
//   even/odd-kb accumulator split -> 4 independent MFMA chains per wave
//   (chain depth 4, was 1 chain depth 8).  Toeplitz sharing: tileB frag(kb)
//   == tileA frag(kb+4), so 12 ds_read_b128 feed 16 MFMAs.
//   Stores: 4 precomputed row pointers + immediate offsets (no per-store
//   64-bit VALU).  __launch_bounds__(256,4) caps VGPR at 128 -> 4 waves/SIMD.
// Block: 4 waves x 256 t = 1024 t, one f-block (16 filters), one batch n.
// ---------------------------------------------------------------------------
__global__ __launch_bounds__(TPB, 4) void sinc_mfma_kernel(
    const float* __restrict__ x,
    const unsigned short* __restrict__ fh,
    float* __restrict__ out)
{
    __shared__ __align__(16) unsigned xf[NREP * LROW];  // fp16 pairs in dwords

    const int tid   = threadIdx.x;
    const int strip = blockIdx.x;
    const int fb    = blockIdx.y;
    const int n     = blockIdx.z;
    const int e0    = strip * STRIP;
    const float* xp = x + (size_t)n * SIG_LEN;

    // ---- stage x: fp16, 8 shifted replicas (replica r, dword d = elems 2d+r,2d+r+1)
    for (int d = tid; d < LROW; d += TPB) {
        const int g = e0 + 2 * d;
        float v0, v1, v2;
        if (g + 2 < SIG_LEN) {
            float2 p = *(const float2*)(xp + g);
            v0 = p.x; v1 = p.y; v2 = xp[g + 2];
        } else {
            v0 = (g     < SIG_LEN) ? xp[g]     : 0.0f;
            v1 = (g + 1 < SIG_LEN) ? xp[g + 1] : 0.0f;
            v2 = (g + 2 < SIG_LEN) ? xp[g + 2] : 0.0f;
        }
        const _Float16 h0 = (_Float16)v0, h1 = (_Float16)v1, h2 = (_Float16)v2;
        union { _Float16 h[2]; unsigned u; } pe, po;
        pe.h[0] = h0; pe.h[1] = h1;          // elems 2d, 2d+1
        po.h[0] = h1; po.h[1] = h2;          // elems 2d+1, 2d+2
        xf[0 * LROW + d] = pe.u;                                  // r=0
        xf[1 * LROW + d] = po.u;                                  // r=1
        if (d >= 1) { xf[2 * LROW + d - 1] = pe.u;                // r=2
                      xf[3 * LROW + d - 1] = po.u; }              // r=3
        if (d >= 2) { xf[4 * LROW + d - 2] = pe.u;                // r=4
                      xf[5 * LROW + d - 2] = po.u; }              // r=5
        if (d >= 3) { xf[6 * LROW + d - 3] = pe.u;                // r=6
                      xf[7 * LROW + d - 3] = po.u; }              // r=7
    }

    // ---- A fragments: 16 filters x 256 k, fp16, from global (L2-resident) ---
    const int lane = tid & 63;
    const int w    = tid >> 6;
    const int m    = lane & 15;       // A-row (f) / B-col (t) / C-col (t)
    const int q    = lane >> 4;       // quad: k = q*8+j ; C-row = q*4+reg
    short8 Ah[8];
    {
        const unsigned short* ph = fh + (fb * 16 + m) * KPAD + q * 8;
        #pragma unroll
        for (int kb = 0; kb < 8; ++kb)
            Ah[kb] = *(const short8*)(ph + kb * 32);
    }
    __syncthreads();

    // ---- main loop ---------------------------------------------------------
    // element start s = 256w + 16tt + m + 8q + 32kb ; replica r = m&7
    // dword idx = LROW*r + 128w + 8*(tt+2kb) + 4*(m>>3) + 4q
    // (LROW/4 = 161 odd -> r*LROW spreads quad-bank groups: per b128 instr
    //  exactly 8 lanes per 128B bank group = conflict-free)
    const int r = m & 7;
    const unsigned base = (unsigned)(r * LROW + 4 * (m >> 3) + 4 * q + 128 * w);

    // Row pointers for C: row = fb*16 + q*4 + rg, col base = e0 + w*256 + m.
    // Per-store address = p{rg} + dword offset (fits 13-bit imm: <=960B).
    const size_t cbase =
        ((size_t)n * N_FILT + fb * 16 + q * 4) * OUT_LEN + (e0 + w * WAVE_T + m);
    float* const p0 = out + cbase;
    float* const p1 = p0 + OUT_LEN;
    float* const p2 = p1 + OUT_LEN;
    float* const p3 = p2 + OUT_LEN;
    const int tcol = e0 + w * WAVE_T + m;   // t of tile tt2=0; tile tt2: +16*tt2

    #pragma unroll 2
    for (int tt2 = 0; tt2 < 8; ++tt2) {
        // 12 distinct B fragments: u = tt2 + 2j, j=0..11
        //   tileA (t-tile tt2):   kb -> frag j=kb
        //   tileB (t-tile tt2+8): kb -> frag j=kb+4
        uint4 F[12];
        const unsigned o0 = base + 8 * tt2;
        #pragma unroll
        for (int j = 0; j < 12; ++j)
            F[j] = *(const uint4*)(&xf[o0 + 16 * j]);   // ds_read_b128

        float4v a0 = {0.f,0.f,0.f,0.f}, a1 = {0.f,0.f,0.f,0.f};
        float4v b0 = {0.f,0.f,0.f,0.f}, b1 = {0.f,0.f,0.f,0.f};
        #pragma unroll
        for (int kk = 0; kk < 4; ++kk) {    // 4 independent chains, depth 4
            a0 = __builtin_amdgcn_mfma_f32_16x16x32_f16(
                     __builtin_bit_cast(half8, Ah[2*kk]),
                     __builtin_bit_cast(half8, F[2*kk]),     a0, 0, 0, 0);
            a1 = __builtin_amdgcn_mfma_f32_16x16x32_f16(
                     __builtin_bit_cast(half8, Ah[2*kk+1]),
                     __builtin_bit_cast(half8, F[2*kk+1]),   a1, 0, 0, 0);
            b0 = __builtin_amdgcn_mfma_f32_16x16x32_f16(
                     __builtin_bit_cast(half8, Ah[2*kk]),
                     __builtin_bit_cast(half8, F[2*kk+4]),   b0, 0, 0, 0);
            b1 = __builtin_amdgcn_mfma_f32_16x16x32_f16(
                     __builtin_bit_cast(half8, Ah[2*kk+1]),
                     __builtin_bit_cast(half8, F[2*kk+5]),   b1, 0, 0, 0);
        }

        const int dA = tt2 * 16;            // dword offset of tileA in row
        const int dB = dA + 128;            // tileB
        if (tcol + dA < OUT_LEN) {
            p0[dA] = a0[0] + a1[0];
            p1[dA] = a0[1] + a1[1];
            p2[dA] = a0[2] + a1[2];
            p3[dA] = a0[3] + a1[3];
        }
        if (tcol + dB < OUT_LEN) {
            p0[dB] = b0[0] + b1[0];
            p1[dB] = b0[1] + b1[1];
            p2[dB] = b0[2] + b1[2];
            p3[dB] = b0[3] + b1[3];
        }
    }
}

// ---------------------------------------------------------------------------
extern "C" void kernel_launch(void* const* d_in, const int* in_sizes, int n_in,
                              void* d_out, int out_size, void* d_ws, size_t ws_size,
                              hipStream_t stream)
{
    const float* x    = (const float*)d_in[0];
    const float* b1   = (const float*)d_in[1];
    const float* band = (const float*)d_in[2];
    float* outp = (float*)d_out;

    unsigned short* fh = (unsigned short*)d_ws;          // 80*256*2 B = 40 KB

    build_filters_kernel<<<dim3(N_FILT), dim3(TPB), 0, stream>>>(b1, band, fh);

    dim3 grid((OUT_LEN + STRIP - 1) / STRIP, N_FILT / 16, BATCH);   // 32 x 5 x 32
    sinc_mfma_kernel<<<grid, dim3(TPB), 0, stream>>>(x, fh, outp);
}

// Round 4
// 105.246 us; speedup vs baseline: 1.0666x; 1.0433x over previous
//
#include <hip/hip_runtime.h>
#include <math.h>

#define N_FILT   80
#define FILT_DIM 251
#define KPAD     256
#define SIG_LEN  32000
#define OUT_LEN  31750
#define BATCH    32
#define TPB      256

#define STRIP    1024      // t-range per block
#define WAVE_T   256       // t-range per wave (4 waves)
#define NREP     8         // shifted replicas -> every window is 16B aligned
#define LROW     644       // dwords per replica: %4==0 (16B align), /4 odd (bank spread)
#define OBSTRIDE 66        // out-buffer row stride (dwords): even (b64 align), %32==2 (bank spread)

#define TWO_PI_F 6.28318530717958647692f

typedef __attribute__((ext_vector_type(8))) short    short8;   // raw 16B frag
typedef __attribute__((ext_vector_type(8))) _Float16 half8;    // fp16 A/B frag
typedef __attribute__((ext_vector_type(4))) float    float4v;  // C/D frag

// ---------------------------------------------------------------------------
// Kernel 1: build 80 sinc band-pass filters directly in fp16.
// ---------------------------------------------------------------------------
__global__ __launch_bounds__(TPB) void build_filters_kernel(
    const float* __restrict__ b1, const float* __restrict__ band,
    unsigned short* __restrict__ fh)
{
    const int f = blockIdx.x;
    const int i = threadIdx.x;

    const float MINF = 50.0f / 16000.0f;
    const float fb = fabsf(b1[f]) + MINF;
    const float fe = fb + fabsf(band[f]) + MINF;

    float v = 0.0f;
    if (i < FILT_DIM) {
        int m = i - 125; m = (m < 0) ? -m : m;
        if (m == 0) v = 2.0f * fe - 2.0f * fb;
        else {
            float a1 = TWO_PI_F * fb * (float)m;
            float a2 = TWO_PI_F * fe * (float)m;
            v = 2.0f * fe * (sinf(a2) / a2) - 2.0f * fb * (sinf(a1) / a1);
        }
    }

    __shared__ float red[TPB];
    red[i] = (i < FILT_DIM) ? v : -INFINITY;
    __syncthreads();
    #pragma unroll
    for (int s = TPB / 2; s > 0; s >>= 1) {
        if (i < s) red[i] = fmaxf(red[i], red[i + s]);
        __syncthreads();
    }
    const float mx = red[0];

    const float w   = 0.54f - 0.46f * cosf(TWO_PI_F * (float)i / 250.0f);
    const float val = (i < FILT_DIM) ? (v / mx) * w : 0.0f;
    const _Float16 h = (_Float16)val;                 // RNE v_cvt_f16_f32
    fh[f * KPAD + i] = __builtin_bit_cast(unsigned short, h);  // pad rows = 0
}

// ---------------------------------------------------------------------------
// Kernel 2: conv as MFMA GEMM (fp16), write-coalesced epilogue.
//   C[f,t] = sum_k F[f,k] * x[t+k]
//   A: register fp16 filter frags.  B: Toeplitz x from LDS (8 shifted
//   replicas, aligned ds_read_b128).
//   R4: per-wave LDS out-buffer (16 rows x 64 cols, stride 66); flush each
//   64-col group with float2 stores arranged as 2 rows x 256 B contiguous
//   per instruction (4x longer HBM bursts, 4x fewer store instrs) --
//   testing the "write-bound at half BW due to 64B-granular scatter" theory.
// Block: 4 waves x 256 t = 1024 t, one f-block (16 filters), one batch n.
// ---------------------------------------------------------------------------
__global__ __launch_bounds__(TPB, 4) void sinc_mfma_kernel(
    const float* __restrict__ x,
    const unsigned short* __restrict__ fh,
    float* __restrict__ out)
{
    __shared__ __align__(16) unsigned xf[NREP * LROW];   // 20.6 KB
    __shared__ __align__(16) float    ob[4][16 * OBSTRIDE]; // 16.9 KB (4 waves)

    const int tid   = threadIdx.x;
    const int strip = blockIdx.x;
    const int fb    = blockIdx.y;
    const int n     = blockIdx.z;
    const int e0    = strip * STRIP;
    const float* xp = x + (size_t)n * SIG_LEN;

    // ---- stage x: fp16, 8 shifted replicas (replica r, dword d = elems 2d+r,2d+r+1)
    for (int d = tid; d < LROW; d += TPB) {
        const int g = e0 + 2 * d;
        float v0, v1, v2;
        if (g + 2 < SIG_LEN) {
            float2 p = *(const float2*)(xp + g);
            v0 = p.x; v1 = p.y; v2 = xp[g + 2];
        } else {
            v0 = (g     < SIG_LEN) ? xp[g]     : 0.0f;
            v1 = (g + 1 < SIG_LEN) ? xp[g + 1] : 0.0f;
            v2 = (g + 2 < SIG_LEN) ? xp[g + 2] : 0.0f;
        }
        const _Float16 h0 = (_Float16)v0, h1 = (_Float16)v1, h2 = (_Float16)v2;
        union { _Float16 h[2]; unsigned u; } pe, po;
        pe.h[0] = h0; pe.h[1] = h1;          // elems 2d, 2d+1
        po.h[0] = h1; po.h[1] = h2;          // elems 2d+1, 2d+2
        xf[0 * LROW + d] = pe.u;                                  // r=0
        xf[1 * LROW + d] = po.u;                                  // r=1
        if (d >= 1) { xf[2 * LROW + d - 1] = pe.u;                // r=2
                      xf[3 * LROW + d - 1] = po.u; }              // r=3
        if (d >= 2) { xf[4 * LROW + d - 2] = pe.u;                // r=4
                      xf[5 * LROW + d - 2] = po.u; }              // r=5
        if (d >= 3) { xf[6 * LROW + d - 3] = pe.u;                // r=6
                      xf[7 * LROW + d - 3] = po.u; }              // r=7
    }

    // ---- A fragments: 16 filters x 256 k, fp16, from global (L2-resident) ---
    const int lane = tid & 63;
    const int w    = tid >> 6;
    const int m    = lane & 15;       // A-row (f) / B-col (t) / C-col (t)
    const int q    = lane >> 4;       // quad: k = q*8+j ; C-row = q*4+reg
    short8 Ah[8];
    {
        const unsigned short* ph = fh + (fb * 16 + m) * KPAD + q * 8;
        #pragma unroll
        for (int kb = 0; kb < 8; ++kb)
            Ah[kb] = *(const short8*)(ph + kb * 32);
    }
    __syncthreads();

    // ---- main loop ---------------------------------------------------------
    // element start s = 256w + 16tt + m + 8q + 32kb ; replica r = m&7
    // dword idx = LROW*r + 128w + 8*(tt+2kb) + 4*(m>>3) + 4q  (conflict-free)
    const int r = m & 7;
    const unsigned base = (unsigned)(r * LROW + 4 * (m >> 3) + 4 * q + 128 * w);

    float* const obw = &ob[w][0];
    const int    c2    = 2 * (lane & 31);        // flush: group-local col pair
    const int    rhalf = lane >> 5;              // flush: row half
    const size_t rowb  = ((size_t)n * N_FILT + fb * 16) * OUT_LEN;

    for (int g = 0; g < 4; ++g) {                // 4 groups of 64 cols
        #pragma unroll
        for (int tl = 0; tl < 4; ++tl) {         // 4 tiles per group
            const int tt = g * 4 + tl;
            float4v a0 = {0.f,0.f,0.f,0.f}, a1 = {0.f,0.f,0.f,0.f};
            const unsigned o0 = base + 8 * tt;
            #pragma unroll
            for (int kk = 0; kk < 4; ++kk) {     // kb = 2kk (a0), 2kk+1 (a1)
                a0 = __builtin_amdgcn_mfma_f32_16x16x32_f16(
                         __builtin_bit_cast(half8, Ah[2*kk]),
                         __builtin_bit_cast(half8, *(const uint4*)(&xf[o0 + 32*kk])),
                         a0, 0, 0, 0);
                a1 = __builtin_amdgcn_mfma_f32_16x16x32_f16(
                         __builtin_bit_cast(half8, Ah[2*kk+1]),
                         __builtin_bit_cast(half8, *(const uint4*)(&xf[o0 + 32*kk + 16])),
                         a1, 0, 0, 0);
            }
            const int oc = tl * 16 + m;          // group-local col
            #pragma unroll
            for (int rg = 0; rg < 4; ++rg)
                obw[(q * 4 + rg) * OBSTRIDE + oc] = a0[rg] + a1[rg];
        }

        // ---- flush group g: 8 x float2 stores, 2 rows x 256 B contiguous --
        const int t = e0 + w * WAVE_T + g * 64 + c2;
        if (t + 1 < OUT_LEN) {                   // OUT_LEN even, t even: no partials
            #pragma unroll
            for (int f = 0; f < 8; ++f) {
                const int rr = 2 * f + rhalf;
                const float2 v = *(const float2*)(&obw[rr * OBSTRIDE + c2]);
                *(float2*)(out + rowb + (size_t)rr * OUT_LEN + t) = v;
            }
        }
    }
}

// ---------------------------------------------------------------------------
extern "C" void kernel_launch(void* const* d_in, const int* in_sizes, int n_in,
                              void* d_out, int out_size, void* d_ws, size_t ws_size,
                              hipStream_t stream)
{
    const float* x    = (const float*)d_in[0];
    const float* b1   = (const float*)d_in[1];
    const float* band = (const float*)d_in[2];
    float* outp = (float*)d_out;

    unsigned short* fh = (unsigned short*)d_ws;          // 80*256*2 B = 40 KB

    build_filters_kernel<<<dim3(N_FILT), dim3(TPB), 0, stream>>>(b1, band, fh);

    dim3 grid((OUT_LEN + STRIP - 1) / STRIP, N_FILT / 16, BATCH);   // 32 x 5 x 32
    sinc_mfma_kernel<<<grid, dim3(TPB), 0, stream>>>(x, fh, outp);
}

// Round 5
// 102.146 us; speedup vs baseline: 1.0990x; 1.0303x over previous
//
#include <hip/hip_runtime.h>
#include <math.h>

#define N_FILT   80
#define FILT_DIM 251
#define KPAD     256
#define SIG_LEN  32000
#define OUT_LEN  31750
#define BATCH    32
#define TPB      256

#define STRIP    1024      // t-range per block
#define NREP     8         // shifted replicas -> every window is 16B aligned
#define LROW     644       // dwords per replica: %4==0 (16B align), /4 odd (bank spread)
#define OBS      516       // out-buffer row stride (dwords): %4==0, %32==4 (2-way-free)

#define TWO_PI_F 6.28318530717958647692f

typedef __attribute__((ext_vector_type(8))) short    short8;   // raw 16B frag
typedef __attribute__((ext_vector_type(8))) _Float16 half8;    // fp16 A/B frag
typedef __attribute__((ext_vector_type(4))) float    float4v;  // C/D frag

// ---------------------------------------------------------------------------
// Kernel 1: build 80 sinc band-pass filters directly in fp16.
// ---------------------------------------------------------------------------
__global__ __launch_bounds__(TPB) void build_filters_kernel(
    const float* __restrict__ b1, const float* __restrict__ band,
    unsigned short* __restrict__ fh)
{
    const int f = blockIdx.x;
    const int i = threadIdx.x;

    const float MINF = 50.0f / 16000.0f;
    const float fb = fabsf(b1[f]) + MINF;
    const float fe = fb + fabsf(band[f]) + MINF;

    float v = 0.0f;
    if (i < FILT_DIM) {
        int m = i - 125; m = (m < 0) ? -m : m;
        if (m == 0) v = 2.0f * fe - 2.0f * fb;
        else {
            float a1 = TWO_PI_F * fb * (float)m;
            float a2 = TWO_PI_F * fe * (float)m;
            v = 2.0f * fe * (sinf(a2) / a2) - 2.0f * fb * (sinf(a1) / a1);
        }
    }

    __shared__ float red[TPB];
    red[i] = (i < FILT_DIM) ? v : -INFINITY;
    __syncthreads();
    #pragma unroll
    for (int s = TPB / 2; s > 0; s >>= 1) {
        if (i < s) red[i] = fmaxf(red[i], red[i + s]);
        __syncthreads();
    }
    const float mx = red[0];

    const float w   = 0.54f - 0.46f * cosf(TWO_PI_F * (float)i / 250.0f);
    const float val = (i < FILT_DIM) ? (v / mx) * w : 0.0f;
    const _Float16 h = (_Float16)val;                 // RNE v_cvt_f16_f32
    fh[f * KPAD + i] = __builtin_bit_cast(unsigned short, h);  // pad rows = 0
}

// ---------------------------------------------------------------------------
// Kernel 2: conv as MFMA GEMM (fp16), DRAM-page-coherent epilogue.
//   C[f,t] = sum_k F[f,k] * x[t+k]
//   Wave->column interleave: t = e0 + tt*64 + w*16 + m, so the 4 waves
//   jointly cover 512 consecutive cols per 8-tile phase.  Whole block
//   gathers 16 rows x 512 cols in LDS (ob), then flushes with each wave
//   sweeping 4 ENTIRE rows: 4 consecutive float2 stores = 2 KB sequential
//   per row event (8x R4's 256 B) -- testing the DRAM-page-locality theory
//   of the 2x write-efficiency gap vs the fill kernel.
// Block: 4 waves, 1024 t, one f-block (16 filters), one batch n.
// LDS: 20.6 KB staging + 33 KB ob = 53.6 KB -> 2 blocks/CU.
// ---------------------------------------------------------------------------
__global__ __launch_bounds__(TPB) void sinc_mfma_kernel(
    const float* __restrict__ x,
    const unsigned short* __restrict__ fh,
    float* __restrict__ out)
{
    __shared__ __align__(16) unsigned xf[NREP * LROW];   // 20.6 KB
    __shared__ __align__(16) float    ob[16 * OBS];      // 33.0 KB

    const int tid   = threadIdx.x;
    const int strip = blockIdx.x;
    const int fb    = blockIdx.y;
    const int n     = blockIdx.z;
    const int e0    = strip * STRIP;
    const float* xp = x + (size_t)n * SIG_LEN;

    // ---- stage x: fp16, 8 shifted replicas (replica r, dword d = elems 2d+r,2d+r+1)
    for (int d = tid; d < LROW; d += TPB) {
        const int g = e0 + 2 * d;
        float v0, v1, v2;
        if (g + 2 < SIG_LEN) {
            float2 p = *(const float2*)(xp + g);
            v0 = p.x; v1 = p.y; v2 = xp[g + 2];
        } else {
            v0 = (g     < SIG_LEN) ? xp[g]     : 0.0f;
            v1 = (g + 1 < SIG_LEN) ? xp[g + 1] : 0.0f;
            v2 = (g + 2 < SIG_LEN) ? xp[g + 2] : 0.0f;
        }
        const _Float16 h0 = (_Float16)v0, h1 = (_Float16)v1, h2 = (_Float16)v2;
        union { _Float16 h[2]; unsigned u; } pe, po;
        pe.h[0] = h0; pe.h[1] = h1;          // elems 2d, 2d+1
        po.h[0] = h1; po.h[1] = h2;          // elems 2d+1, 2d+2
        xf[0 * LROW + d] = pe.u;                                  // r=0
        xf[1 * LROW + d] = po.u;                                  // r=1
        if (d >= 1) { xf[2 * LROW + d - 1] = pe.u;                // r=2
                      xf[3 * LROW + d - 1] = po.u; }              // r=3
        if (d >= 2) { xf[4 * LROW + d - 2] = pe.u;                // r=4
                      xf[5 * LROW + d - 2] = po.u; }              // r=5
        if (d >= 3) { xf[6 * LROW + d - 3] = pe.u;                // r=6
                      xf[7 * LROW + d - 3] = po.u; }              // r=7
    }

    // ---- A fragments: 16 filters x 256 k, fp16, from global (L2-resident) ---
    const int lane = tid & 63;
    const int w    = tid >> 6;
    const int m    = lane & 15;       // B-col (t offset) / C-col
    const int q    = lane >> 4;       // quad: k = q*8+j ; C-row = q*4+reg
    short8 Ah[8];
    {
        const unsigned short* ph = fh + (fb * 16 + m) * KPAD + q * 8;
        #pragma unroll
        for (int kb = 0; kb < 8; ++kb)
            Ah[kb] = *(const short8*)(ph + kb * 32);
    }
    __syncthreads();

    // ---- main loop ---------------------------------------------------------
    // element start s = 64*tt + 16*w + m + 8q + 32kb ; replica r = m&7
    // dword idx = LROW*r + 32*tt + 8*w + 4*(m>>3) + 4*q + 16*kb  (16B-aligned)
    const int r = m & 7;
    const unsigned base = (unsigned)(r * LROW + 8 * w + 4 * (m >> 3) + 4 * q);

    const size_t outrow0 = ((size_t)n * N_FILT + fb * 16) * OUT_LEN;

    for (int p = 0; p < 2; ++p) {                 // two 512-col phases
        #pragma unroll
        for (int tg = 0; tg < 8; ++tg) {
            const int tt = p * 8 + tg;
            float4v a0 = {0.f,0.f,0.f,0.f}, a1 = {0.f,0.f,0.f,0.f};
            const unsigned o0 = base + 32u * tt;
            #pragma unroll
            for (int kk = 0; kk < 4; ++kk) {      // kb = 2kk (a0), 2kk+1 (a1)
                a0 = __builtin_amdgcn_mfma_f32_16x16x32_f16(
                         __builtin_bit_cast(half8, Ah[2*kk]),
                         __builtin_bit_cast(half8, *(const uint4*)(&xf[o0 + 32*kk])),
                         a0, 0, 0, 0);
                a1 = __builtin_amdgcn_mfma_f32_16x16x32_f16(
                         __builtin_bit_cast(half8, Ah[2*kk+1]),
                         __builtin_bit_cast(half8, *(const uint4*)(&xf[o0 + 32*kk + 16])),
                         a1, 0, 0, 0);
            }
            const int oc = tg * 64 + w * 16 + m;  // phase-local col
            #pragma unroll
            for (int rg = 0; rg < 4; ++rg)
                ob[(q * 4 + rg) * OBS + oc] = a0[rg] + a1[rg];
        }
        __syncthreads();

        // ---- flush phase p: wave w sweeps rows 4w..4w+3, 512 cols each ----
        // 4 consecutive float2 instrs per row = 2 KB sequential per row event.
        #pragma unroll
        for (int j = 0; j < 4; ++j) {
            const int row = 4 * w + j;
            float* const dst = out + outrow0 + (size_t)row * OUT_LEN;
            #pragma unroll
            for (int h = 0; h < 4; ++h) {
                const int c  = h * 128 + 2 * lane;
                const int t0 = e0 + p * 512 + c;
                if (t0 + 1 < OUT_LEN) {
                    const float2 v = *(const float2*)(&ob[row * OBS + c]);
                    *(float2*)(dst + t0) = v;
                } else if (t0 < OUT_LEN) {
                    dst[t0] = ob[row * OBS + c];
                }
            }
        }
        __syncthreads();
    }
}

// ---------------------------------------------------------------------------
extern "C" void kernel_launch(void* const* d_in, const int* in_sizes, int n_in,
                              void* d_out, int out_size, void* d_ws, size_t ws_size,
                              hipStream_t stream)
{
    const float* x    = (const float*)d_in[0];
    const float* b1   = (const float*)d_in[1];
    const float* band = (const float*)d_in[2];
    float* outp = (float*)d_out;

    unsigned short* fh = (unsigned short*)d_ws;          // 80*256*2 B = 40 KB

    build_filters_kernel<<<dim3(N_FILT), dim3(TPB), 0, stream>>>(b1, band, fh);

    dim3 grid((OUT_LEN + STRIP - 1) / STRIP, N_FILT / 16, BATCH);   // 32 x 5 x 32
    sinc_mfma_kernel<<<grid, dim3(TPB), 0, stream>>>(x, fh, outp);
}

// Round 6
// 93.220 us; speedup vs baseline: 1.2042x; 1.0958x over previous
//
#include <hip/hip_runtime.h>
#include <math.h>

#define N_FILT   80
#define FILT_DIM 251
#define KPAD     256
#define SIG_LEN  32000
#define OUT_LEN  31750
#define BATCH    32
#define TPB      320       // 5 waves: wave w owns filter-block fb = w

#define STRIP    1024      // t-range per block
#define NREP     8         // shifted replicas -> every window is 16B aligned
#define LROW     644       // dwords per replica: %4==0 (16B align), /4 odd (bank spread)
#define OBS      80        // out-buffer row stride (dwords): %32==16 -> 2-way max
#define NTILE    64        // 16-col tiles per wave (1024 cols)

#define TWO_PI_F 6.28318530717958647692f

typedef __attribute__((ext_vector_type(8))) short    short8;   // raw 16B frag
typedef __attribute__((ext_vector_type(8))) _Float16 half8;    // fp16 A/B frag
typedef __attribute__((ext_vector_type(4))) float    float4v;  // C/D frag

// ---------------------------------------------------------------------------
// Kernel 1: build 80 sinc band-pass filters directly in fp16.
// ---------------------------------------------------------------------------
__global__ __launch_bounds__(256) void build_filters_kernel(
    const float* __restrict__ b1, const float* __restrict__ band,
    unsigned short* __restrict__ fh)
{
    const int f = blockIdx.x;
    const int i = threadIdx.x;

    const float MINF = 50.0f / 16000.0f;
    const float fb = fabsf(b1[f]) + MINF;
    const float fe = fb + fabsf(band[f]) + MINF;

    float v = 0.0f;
    if (i < FILT_DIM) {
        int m = i - 125; m = (m < 0) ? -m : m;
        if (m == 0) v = 2.0f * fe - 2.0f * fb;
        else {
            float a1 = TWO_PI_F * fb * (float)m;
            float a2 = TWO_PI_F * fe * (float)m;
            v = 2.0f * fe * (sinf(a2) / a2) - 2.0f * fb * (sinf(a1) / a1);
        }
    }

    __shared__ float red[256];
    red[i] = (i < FILT_DIM) ? v : -INFINITY;
    __syncthreads();
    #pragma unroll
    for (int s = 128; s > 0; s >>= 1) {
        if (i < s) red[i] = fmaxf(red[i], red[i + s]);
        __syncthreads();
    }
    const float mx = red[0];

    const float w   = 0.54f - 0.46f * cosf(TWO_PI_F * (float)i / 250.0f);
    const float val = (i < FILT_DIM) ? (v / mx) * w : 0.0f;
    const _Float16 h = (_Float16)val;                 // RNE v_cvt_f16_f32
    fh[f * KPAD + i] = __builtin_bit_cast(unsigned short, h);  // pad rows = 0
}

// ---------------------------------------------------------------------------
// Kernel 2: conv as MFMA GEMM (fp16), wave-independent structure.
//   C[f,t] = sum_k F[f,k] * x[t+k]
//   R6: block = 5 waves; wave w owns fb=w (16 filters) x all 1024 cols.
//     - x staged ONCE per (strip,n)  (was 5x: once per fb)
//     - ONE barrier total; flushes are wave-private (own ob region, own
//       output rows) -> no __syncthreads -> no s_waitcnt vmcnt(0) drains;
//       stores pipeline freely until kernel end.
//     - grid 1024 blocks, XCD-swizzled: each XCD owns 4 contiguous batches.
//   LDS: 20.6 KB staging + 25.6 KB ob = 46.2 KB -> 3 blocks/CU (15 waves).
// ---------------------------------------------------------------------------
__global__ __launch_bounds__(TPB, 4) void sinc_mfma_kernel(
    const float* __restrict__ x,
    const unsigned short* __restrict__ fh,
    float* __restrict__ out)
{
    __shared__ __align__(16) unsigned xf[NREP * LROW];     // 20.6 KB
    __shared__ __align__(16) float    ob[5][16 * OBS];     // 25.6 KB

    const int tid = threadIdx.x;
    // XCD swizzle: raw%8 = XCD -> give each XCD a contiguous run of 128
    // blocks = 4 complete batches (contiguous 1/8 of the output buffer).
    const unsigned raw = blockIdx.x;
    const unsigned swz = (raw & 7u) * 128u + (raw >> 3);
    const int strip = (int)(swz & 31u);
    const int n     = (int)(swz >> 5);
    const int e0    = strip * STRIP;
    const float* xp = x + (size_t)n * SIG_LEN;

    // ---- stage x: fp16, 8 shifted replicas (replica r, dword d = elems 2d+r,2d+r+1)
    for (int d = tid; d < LROW; d += TPB) {
        const int g = e0 + 2 * d;
        float v0, v1, v2;
        if (g + 2 < SIG_LEN) {
            float2 p = *(const float2*)(xp + g);
            v0 = p.x; v1 = p.y; v2 = xp[g + 2];
        } else {
            v0 = (g     < SIG_LEN) ? xp[g]     : 0.0f;
            v1 = (g + 1 < SIG_LEN) ? xp[g + 1] : 0.0f;
            v2 = (g + 2 < SIG_LEN) ? xp[g + 2] : 0.0f;
        }
        const _Float16 h0 = (_Float16)v0, h1 = (_Float16)v1, h2 = (_Float16)v2;
        union { _Float16 h[2]; unsigned u; } pe, po;
        pe.h[0] = h0; pe.h[1] = h1;          // elems 2d, 2d+1
        po.h[0] = h1; po.h[1] = h2;          // elems 2d+1, 2d+2
        xf[0 * LROW + d] = pe.u;                                  // r=0
        xf[1 * LROW + d] = po.u;                                  // r=1
        if (d >= 1) { xf[2 * LROW + d - 1] = pe.u;                // r=2
                      xf[3 * LROW + d - 1] = po.u; }              // r=3
        if (d >= 2) { xf[4 * LROW + d - 2] = pe.u;                // r=4
                      xf[5 * LROW + d - 2] = po.u; }              // r=5
        if (d >= 3) { xf[6 * LROW + d - 3] = pe.u;                // r=6
                      xf[7 * LROW + d - 3] = po.u; }              // r=7
    }

    // ---- A fragments: wave w reads its 16 filters (fb = w) ------------------
    const int lane = tid & 63;
    const int w    = tid >> 6;        // wave id == filter-block
    const int m    = lane & 15;       // B-col (t offset) / C-col
    const int q    = lane >> 4;       // quad: k = q*8+j ; C-row = q*4+reg
    short8 Ah[8];
    {
        const unsigned short* ph = fh + (w * 16 + m) * KPAD + q * 8;
        #pragma unroll
        for (int kb = 0; kb < 8; ++kb)
            Ah[kb] = *(const short8*)(ph + kb * 32);
    }
    __syncthreads();                  // the ONLY barrier

    // ---- main loop: 64 t-tiles, flush every 4 (wave-private, no barriers) --
    // element start s = 16*tt + m + 8q + 32kb ; replica r = m&7
    // dword idx = LROW*r + 8*tt + 4*(m>>3) + 4*q + 16*kb  (16B-aligned,
    // balanced 8 lanes per 16B bank group per b128 -> conflict-free)
    const int r = m & 7;
    const unsigned base = (unsigned)(r * LROW + 4 * (m >> 3) + 4 * q);

    float* const obw  = &ob[w][0];
    const int    c2   = 2 * (lane & 31);       // flush: group-local col pair
    const int    rh   = lane >> 5;             // flush: row parity
    const size_t row0 = ((size_t)n * N_FILT + w * 16) * OUT_LEN;

    for (int g = 0; g < 16; ++g) {             // 16 groups of 64 cols
        #pragma unroll
        for (int tl = 0; tl < 4; ++tl) {
            const int tt = g * 4 + tl;
            float4v a0 = {0.f,0.f,0.f,0.f}, a1 = {0.f,0.f,0.f,0.f};
            const unsigned o0 = base + 8u * tt;
            #pragma unroll
            for (int kk = 0; kk < 4; ++kk) {   // kb = 2kk (a0), 2kk+1 (a1)
                a0 = __builtin_amdgcn_mfma_f32_16x16x32_f16(
                         __builtin_bit_cast(half8, Ah[2*kk]),
                         __builtin_bit_cast(half8, *(const uint4*)(&xf[o0 + 32*kk])),
                         a0, 0, 0, 0);
                a1 = __builtin_amdgcn_mfma_f32_16x16x32_f16(
                         __builtin_bit_cast(half8, Ah[2*kk+1]),
                         __builtin_bit_cast(half8, *(const uint4*)(&xf[o0 + 32*kk + 16])),
                         a1, 0, 0, 0);
            }
            const int oc = tl * 16 + m;        // group-local col
            #pragma unroll
            for (int rg = 0; rg < 4; ++rg)
                obw[(q * 4 + rg) * OBS + oc] = a0[rg] + a1[rg];
        }

        // flush group g: 8 float2 stores (2 rows x 256 B each), per-lane guard
        const int t0 = e0 + g * 64 + c2;       // even -> no partial float2
        if (t0 + 1 < OUT_LEN) {
            #pragma unroll
            for (int f = 0; f < 8; ++f) {
                const int row = 2 * f + rh;
                const float2 v = *(const float2*)(&obw[row * OBS + c2]);
                *(float2*)(out + row0 + (size_t)row * OUT_LEN + t0) = v;
            }
        }
    }
}

// ---------------------------------------------------------------------------
extern "C" void kernel_launch(void* const* d_in, const int* in_sizes, int n_in,
                              void* d_out, int out_size, void* d_ws, size_t ws_size,
                              hipStream_t stream)
{
    const float* x    = (const float*)d_in[0];
    const float* b1   = (const float*)d_in[1];
    const float* band = (const float*)d_in[2];
    float* outp = (float*)d_out;

    unsigned short* fh = (unsigned short*)d_ws;          // 80*256*2 B = 40 KB

    build_filters_kernel<<<dim3(N_FILT), dim3(256), 0, stream>>>(b1, band, fh);

    dim3 grid(32 * 32);                                  // (strip, n) swizzled
    sinc_mfma_kernel<<<grid, dim3(TPB), 0, stream>>>(x, fh, outp);
}

// Round 7
// 91.365 us; speedup vs baseline: 1.2286x; 1.0203x over previous
//
#include <hip/hip_runtime.h>
#include <math.h>

#define N_FILT   80
#define FILT_DIM 251
#define KPAD     256
#define SIG_LEN  32000
#define OUT_LEN  31750
#define BATCH    32
#define TPB      320       // 5 waves: wave w owns filter-block fb = w

#define STRIP    1024      // t-range per block
#define NREP     8         // shifted replicas -> every window is 16B aligned
#define LROW     644       // dwords per replica: %4==0 (16B align), /4 odd (bank spread)
#define OBS      80        // out-buffer row stride (dwords): %32==16 -> 2-way max

#define TWO_PI_F 6.28318530717958647692f

typedef __attribute__((ext_vector_type(8))) short    short8;   // raw 16B frag
typedef __attribute__((ext_vector_type(8))) _Float16 half8;    // fp16 A/B frag
typedef __attribute__((ext_vector_type(4))) float    float4v;  // C/D frag

// ---------------------------------------------------------------------------
// Kernel 1: build 80 sinc band-pass filters directly in fp16.
// ---------------------------------------------------------------------------
__global__ __launch_bounds__(256) void build_filters_kernel(
    const float* __restrict__ b1, const float* __restrict__ band,
    unsigned short* __restrict__ fh)
{
    const int f = blockIdx.x;
    const int i = threadIdx.x;

    const float MINF = 50.0f / 16000.0f;
    const float fb = fabsf(b1[f]) + MINF;
    const float fe = fb + fabsf(band[f]) + MINF;

    float v = 0.0f;
    if (i < FILT_DIM) {
        int m = i - 125; m = (m < 0) ? -m : m;
        if (m == 0) v = 2.0f * fe - 2.0f * fb;
        else {
            float a1 = TWO_PI_F * fb * (float)m;
            float a2 = TWO_PI_F * fe * (float)m;
            v = 2.0f * fe * (sinf(a2) / a2) - 2.0f * fb * (sinf(a1) / a1);
        }
    }

    __shared__ float red[256];
    red[i] = (i < FILT_DIM) ? v : -INFINITY;
    __syncthreads();
    #pragma unroll
    for (int s = 128; s > 0; s >>= 1) {
        if (i < s) red[i] = fmaxf(red[i], red[i + s]);
        __syncthreads();
    }
    const float mx = red[0];

    const float w   = 0.54f - 0.46f * cosf(TWO_PI_F * (float)i / 250.0f);
    const float val = (i < FILT_DIM) ? (v / mx) * w : 0.0f;
    const _Float16 h = (_Float16)val;                 // RNE v_cvt_f16_f32
    fh[f * KPAD + i] = __builtin_bit_cast(unsigned short, h);  // pad rows = 0
}

// ---------------------------------------------------------------------------
// Kernel 2: conv as MFMA GEMM (fp16), wave-independent + Toeplitz register
// window.   C[f,t] = sum_k F[f,k] * x[t+k]
//   R7: B fragment for (tt,kb) depends only on u = tt + 2*kb  ->  16-slot
//   rolling register window (prefill u=0..13, then ONE ds_read_b128 per
//   tile).  B-reads/wave: 512 -> 78 (6.6x), modeled LDS busy 70 -> ~25 us.
//   Window slot indices kept compile-time static by unrolling groups x4:
//   slot = (g4*4 + tl + 2kb) & 15  (gg*16 vanishes mod 16).
//   Rest as R6: 5 waves, wave w owns fb=w; staging once; ONE barrier;
//   wave-private ob gather + 2x256B float2 flush, no vmcnt drains.
// LDS 46.2 KB; VGPR ~150 (window 64) -> ~2 blocks/CU (10 waves).
// ---------------------------------------------------------------------------
__global__ __launch_bounds__(TPB, 2) void sinc_mfma_kernel(
    const float* __restrict__ x,
    const unsigned short* __restrict__ fh,
    float* __restrict__ out)
{
    __shared__ __align__(16) unsigned xf[NREP * LROW];     // 20.6 KB
    __shared__ __align__(16) float    ob[5][16 * OBS];     // 25.6 KB

    const int tid = threadIdx.x;
    // XCD swizzle: raw%8 = XCD -> each XCD owns 128 contiguous (strip,n)
    // blocks = 4 complete batches.
    const unsigned raw = blockIdx.x;
    const unsigned swz = (raw & 7u) * 128u + (raw >> 3);
    const int strip = (int)(swz & 31u);
    const int n     = (int)(swz >> 5);
    const int e0    = strip * STRIP;
    const float* xp = x + (size_t)n * SIG_LEN;

    // ---- stage x: fp16, 8 shifted replicas (replica r, dword d = elems 2d+r,2d+r+1)
    for (int d = tid; d < LROW; d += TPB) {
        const int g = e0 + 2 * d;
        float v0, v1, v2;
        if (g + 2 < SIG_LEN) {
            float2 p = *(const float2*)(xp + g);
            v0 = p.x; v1 = p.y; v2 = xp[g + 2];
        } else {
            v0 = (g     < SIG_LEN) ? xp[g]     : 0.0f;
            v1 = (g + 1 < SIG_LEN) ? xp[g + 1] : 0.0f;
            v2 = (g + 2 < SIG_LEN) ? xp[g + 2] : 0.0f;
        }
        const _Float16 h0 = (_Float16)v0, h1 = (_Float16)v1, h2 = (_Float16)v2;
        union { _Float16 h[2]; unsigned u; } pe, po;
        pe.h[0] = h0; pe.h[1] = h1;          // elems 2d, 2d+1
        po.h[0] = h1; po.h[1] = h2;          // elems 2d+1, 2d+2
        xf[0 * LROW + d] = pe.u;                                  // r=0
        xf[1 * LROW + d] = po.u;                                  // r=1
        if (d >= 1) { xf[2 * LROW + d - 1] = pe.u;                // r=2
                      xf[3 * LROW + d - 1] = po.u; }              // r=3
        if (d >= 2) { xf[4 * LROW + d - 2] = pe.u;                // r=4
                      xf[5 * LROW + d - 2] = po.u; }              // r=5
        if (d >= 3) { xf[6 * LROW + d - 3] = pe.u;                // r=6
                      xf[7 * LROW + d - 3] = po.u; }              // r=7
    }

    // ---- A fragments: wave w reads its 16 filters (fb = w) ------------------
    const int lane = tid & 63;
    const int w    = tid >> 6;        // wave id == filter-block
    const int m    = lane & 15;       // B-col (t offset) / C-col
    const int q    = lane >> 4;       // quad: k = q*8+j ; C-row = q*4+reg
    short8 Ah[8];
    {
        const unsigned short* ph = fh + (w * 16 + m) * KPAD + q * 8;
        #pragma unroll
        for (int kb = 0; kb < 8; ++kb)
            Ah[kb] = *(const short8*)(ph + kb * 32);
    }
    __syncthreads();                  // the ONLY barrier

    // ---- main loop: 64 t-tiles, Toeplitz window, flush every 4 tiles -------
    // element start s = 16*tt + m + 8q + 32kb ; replica r = m&7
    // frag dword offset = base + 8*u, u = tt + 2*kb  (16B-aligned, balanced
    // 8 lanes per 16B bank group per b128 -> conflict-free)
    const int r = m & 7;
    const unsigned base = (unsigned)(r * LROW + 4 * (m >> 3) + 4 * q);

    float* const obw  = &ob[w][0];
    const int    c2   = 2 * (lane & 31);       // flush: group-local col pair
    const int    rh   = lane >> 5;             // flush: row parity
    const size_t row0 = ((size_t)n * N_FILT + w * 16) * OUT_LEN;

    uint4 Bw[16];                              // rolling window, slot = u & 15
    #pragma unroll
    for (int u = 0; u < 14; ++u)               // prefill u = 0..13
        Bw[u] = *(const uint4*)(&xf[base + 8u * u]);

    for (int gg = 0; gg < 4; ++gg) {           // 4 super-groups x 16 tiles
        #pragma unroll
        for (int g4 = 0; g4 < 4; ++g4) {       // 4 groups of 4 tiles (64 cols)
            #pragma unroll
            for (int tl = 0; tl < 4; ++tl) {
                const int tt = gg * 16 + g4 * 4 + tl;   // tile index
                // load u = tt+14 into slot (g4*4+tl+14)&15 (static)
                Bw[(g4 * 4 + tl + 14) & 15] =
                    *(const uint4*)(&xf[base + 8u * (unsigned)(tt + 14)]);

                float4v a0 = {0.f,0.f,0.f,0.f}, a1 = {0.f,0.f,0.f,0.f};
                #pragma unroll
                for (int kk = 0; kk < 4; ++kk) {   // kb = 2kk, 2kk+1
                    a0 = __builtin_amdgcn_mfma_f32_16x16x32_f16(
                             __builtin_bit_cast(half8, Ah[2*kk]),
                             __builtin_bit_cast(half8, Bw[(g4*4 + tl + 4*kk) & 15]),
                             a0, 0, 0, 0);
                    a1 = __builtin_amdgcn_mfma_f32_16x16x32_f16(
                             __builtin_bit_cast(half8, Ah[2*kk+1]),
                             __builtin_bit_cast(half8, Bw[(g4*4 + tl + 4*kk + 2) & 15]),
                             a1, 0, 0, 0);
                }
                const int oc = tl * 16 + m;        // group-local col
                #pragma unroll
                for (int rg = 0; rg < 4; ++rg)
                    obw[(q * 4 + rg) * OBS + oc] = a0[rg] + a1[rg];
            }

            // flush group: 8 float2 stores (2 rows x 256 B each)
            const int t0 = e0 + (gg * 4 + g4) * 64 + c2;   // even
            if (t0 + 1 < OUT_LEN) {
                #pragma unroll
                for (int f = 0; f < 8; ++f) {
                    const int row = 2 * f + rh;
                    const float2 v = *(const float2*)(&obw[row * OBS + c2]);
                    *(float2*)(out + row0 + (size_t)row * OUT_LEN + t0) = v;
                }
            }
        }
    }
}

// ---------------------------------------------------------------------------
extern "C" void kernel_launch(void* const* d_in, const int* in_sizes, int n_in,
                              void* d_out, int out_size, void* d_ws, size_t ws_size,
                              hipStream_t stream)
{
    const float* x    = (const float*)d_in[0];
    const float* b1   = (const float*)d_in[1];
    const float* band = (const float*)d_in[2];
    float* outp = (float*)d_out;

    unsigned short* fh = (unsigned short*)d_ws;          // 80*256*2 B = 40 KB

    build_filters_kernel<<<dim3(N_FILT), dim3(256), 0, stream>>>(b1, band, fh);

    dim3 grid(32 * 32);                                  // (strip, n) swizzled
    sinc_mfma_kernel<<<grid, dim3(TPB), 0, stream>>>(x, fh, outp);
}